// Round 5
// baseline (53294.897 us; speedup 1.0000x reference)
//
#include <hip/hip_runtime.h>
#include <hip/hip_bf16.h>

// CharRNN (MI-GRU x2, T=256, B=128, H=1024) + NCE loss.
// Round 5: persistent recurrence kernel (1 dispatch instead of 1024).
// 2 phases/step via layer pipelining (L1 lags one step); two-level atomic grid
// barrier (agent scope) between phases. Per-element math bit-identical to the
// round-4 passing version (same K-chain order, fp32 state, bf16 MFMA operands).

#define T_SEQ 256
#define BATCH 128
#define HD    1024
#define NBLK  256

typedef __attribute__((ext_vector_type(8))) short short8v;
typedef __attribute__((ext_vector_type(4))) float f32x4;

static __device__ __forceinline__ short f2b(float v) {
  __hip_bfloat16 h = __float2bfloat16(v);
  return __builtin_bit_cast(short, h);
}
static __device__ __forceinline__ float b2f(short s) {
  return __bfloat162float(__builtin_bit_cast(__hip_bfloat16, s));
}
static __device__ __forceinline__ float sigm(float x) { return 1.f / (1.f + __expf(-x)); }
static __device__ __forceinline__ float splus(float x) {
  return fmaxf(x, 0.f) + log1pf(__expf(-fabsf(x)));
}

struct Acc22 { f32x4 a[2][2]; };

// ---- legacy 32x32-tile wave GEMM (setup + NCE kernels) ----
static __device__ __forceinline__ void gemm_wave(
    const short* __restrict__ A, int lda, const short* __restrict__ WT, int ldk,
    int row0, int cb, int K, Acc22& o) {
  const int lane = threadIdx.x & 63;
  const int l15 = lane & 15, g = lane >> 4;
  f32x4 z = {0.f, 0.f, 0.f, 0.f};
  o.a[0][0] = z; o.a[0][1] = z; o.a[1][0] = z; o.a[1][1] = z;
  const short* a0 = A + (size_t)(row0 + l15) * lda + g * 8;
  const short* a1 = a0 + 16 * (size_t)lda;
  const short* b0 = WT + (size_t)(cb + l15) * ldk + g * 8;
  const short* b1 = b0 + 16 * (size_t)ldk;
  for (int k = 0; k < K; k += 32) {
    short8v av0 = *(const short8v*)(a0 + k);
    short8v av1 = *(const short8v*)(a1 + k);
    short8v bv0 = *(const short8v*)(b0 + k);
    short8v bv1 = *(const short8v*)(b1 + k);
    o.a[0][0] = __builtin_amdgcn_mfma_f32_16x16x32_bf16(av0, bv0, o.a[0][0], 0, 0, 0);
    o.a[0][1] = __builtin_amdgcn_mfma_f32_16x16x32_bf16(av0, bv1, o.a[0][1], 0, 0, 0);
    o.a[1][0] = __builtin_amdgcn_mfma_f32_16x16x32_bf16(av1, bv0, o.a[1][0], 0, 0, 0);
    o.a[1][1] = __builtin_amdgcn_mfma_f32_16x16x32_bf16(av1, bv1, o.a[1][1], 0, 0, 0);
  }
}

// ---- persistent-kernel 16x16-out tile GEMM: one wave, 16 rows x 16 cols, K=1024 ----
static __device__ __forceinline__ f32x4 tile16(const short* __restrict__ A,
    const short* __restrict__ BT, int cb, int arow, int l15, int g8) {
  f32x4 acc = {0.f, 0.f, 0.f, 0.f};
  const short* ap = A + (size_t)arow * HD + g8;
  const short* bp = BT + (size_t)(cb + l15) * HD + g8;
#pragma unroll 8
  for (int ks = 0; ks < 32; ++ks) {
    short8v av = *(const short8v*)(ap + ks * 32);
    short8v bv = *(const short8v*)(bp + ks * 32);
    acc = __builtin_amdgcn_mfma_f32_16x16x32_bf16(av, bv, acc, 0, 0, 0);
  }
  return acc;
}

struct Params {
  const int *tok, *tgt, *nce;
  const float *emb, *win, *binp;
  const float *ag, *b1g, *b2g, *bg, *ac, *b1c, *b2c, *bc;
  const float *smw, *smb;
  short *embB, *winT, *WhgT0, *WhgT1, *WhcT0, *WhcT1, *WXC0T, *WXC1T;
  short *sampWT;
  float *sampb;
  short *X, *OUTb;
  float *h0f, *h1f; short *h0b, *h1b;
  short *rh0b, *rh1b;
  float *u0, *u1, *cx1;
  float *gxc0a, *gxc0b;
  float *slog;
  float *dout;
};

// ---------- grid barrier (two-level, 16 groups x 16 blocks) ----------
// bar[0]: root count; bar[64]: root generation; bar[128 + grp*64]: group counts.
static __device__ __forceinline__ void gbar(int* bar) {
  __syncthreads();
  if (threadIdx.x == 0) {
    __threadfence();                                   // release this block's writes
    int* rgen = bar + 64;
    int g0 = __hip_atomic_load(rgen, __ATOMIC_RELAXED, __HIP_MEMORY_SCOPE_AGENT);
    int* gcnt = bar + 128 + (blockIdx.x >> 4) * 64;
    if (__hip_atomic_fetch_add(gcnt, 1, __ATOMIC_ACQ_REL, __HIP_MEMORY_SCOPE_AGENT) == 15) {
      __hip_atomic_store(gcnt, 0, __ATOMIC_RELAXED, __HIP_MEMORY_SCOPE_AGENT);
      if (__hip_atomic_fetch_add(bar, 1, __ATOMIC_ACQ_REL, __HIP_MEMORY_SCOPE_AGENT) == 15) {
        __hip_atomic_store(bar, 0, __ATOMIC_RELAXED, __HIP_MEMORY_SCOPE_AGENT);
        __hip_atomic_store(rgen, g0 + 1, __ATOMIC_RELEASE, __HIP_MEMORY_SCOPE_AGENT);
      }
    }
    while (__hip_atomic_load(rgen, __ATOMIC_ACQUIRE, __HIP_MEMORY_SCOPE_AGENT) == g0)
      __builtin_amdgcn_s_sleep(2);
  }
  __syncthreads();
  __threadfence();  // all threads: acquire + L1 invalidate before reading peers' data
}

// ---------- setup kernels ----------

__global__ void k_zero(float* __restrict__ p, int n, float* __restrict__ dout,
                       int* __restrict__ bar) {
  int i = blockIdx.x * 256 + threadIdx.x;
  if (i < n) p[i] = 0.f;
  if (blockIdx.x == 0) {
    for (int j = threadIdx.x; j < 2048; j += 256) bar[j] = 0;
    if (threadIdx.x == 0) *dout = 0.f;
  }
}

__global__ void k_conv(const float* __restrict__ s, short* __restrict__ d, int n) {
  int i = (blockIdx.x * 256 + threadIdx.x) * 4;
  if (i + 4 <= n) {
    float4 v = *(const float4*)(s + i);
    d[i] = f2b(v.x); d[i + 1] = f2b(v.y); d[i + 2] = f2b(v.z); d[i + 3] = f2b(v.w);
  }
}

// W [K][N] fp32 -> WT [N][K] bf16.  grid (N/32, K/32), block (32,8).
__global__ void k_transpose(const float* __restrict__ W, short* __restrict__ WT,
                            int K, int N) {
  __shared__ short tile[32][33];
  int nt = blockIdx.x, kt = blockIdx.y;
  int tx = threadIdx.x, ty = threadIdx.y;
#pragma unroll
  for (int r = 0; r < 4; r++) {
    int k = kt * 32 + ty + r * 8;
    int n = nt * 32 + tx;
    tile[ty + r * 8][tx] = f2b(W[(size_t)k * N + n]);
  }
  __syncthreads();
#pragma unroll
  for (int r = 0; r < 4; r++) {
    int n = nt * 32 + ty + r * 8;
    int k = kt * 32 + tx;
    WT[(size_t)n * K + k] = tile[tx][ty + r * 8];
  }
}

__global__ void k_sampw(Params p) {
  int s = blockIdx.x;                       // 64 sample rows
  int row = p.nce[s];
  for (int j = threadIdx.x; j < HD; j += 256)
    p.sampWT[s * HD + j] = f2b(p.smw[(size_t)row * HD + j]);
  if (threadIdx.x == 0) p.sampb[s] = p.smb[row];
}

// X[t*128+b, :] = embedding[input_data[b,t]] @ win + bin.  grid 8192.
__global__ __launch_bounds__(256) void k_xproj(Params p) {
  int blk = blockIdx.x;
  int mt = blk >> 5, nt = blk & 31;
  int w = threadIdx.x >> 6, lane = threadIdx.x & 63, l15 = lane & 15, g = lane >> 4;
  int row0 = mt * 128 + w * 32, cb = nt * 32;
  const short* ap[2];
#pragma unroll
  for (int mi = 0; mi < 2; mi++) {
    int r = row0 + mi * 16 + l15;
    int tt = r >> 7, bb = r & 127;
    int tk = p.tok[bb * T_SEQ + tt];
    ap[mi] = p.embB + (size_t)tk * 256 + g * 8;
  }
  f32x4 z = {0.f, 0.f, 0.f, 0.f};
  Acc22 acc; acc.a[0][0] = z; acc.a[0][1] = z; acc.a[1][0] = z; acc.a[1][1] = z;
  const short* b0 = p.winT + (size_t)(cb + l15) * 256 + g * 8;
  const short* b1 = b0 + 16 * 256;
  for (int k = 0; k < 256; k += 32) {
    short8v av0 = *(const short8v*)(ap[0] + k);
    short8v av1 = *(const short8v*)(ap[1] + k);
    short8v bv0 = *(const short8v*)(b0 + k);
    short8v bv1 = *(const short8v*)(b1 + k);
    acc.a[0][0] = __builtin_amdgcn_mfma_f32_16x16x32_bf16(av0, bv0, acc.a[0][0], 0, 0, 0);
    acc.a[0][1] = __builtin_amdgcn_mfma_f32_16x16x32_bf16(av0, bv1, acc.a[0][1], 0, 0, 0);
    acc.a[1][0] = __builtin_amdgcn_mfma_f32_16x16x32_bf16(av1, bv0, acc.a[1][0], 0, 0, 0);
    acc.a[1][1] = __builtin_amdgcn_mfma_f32_16x16x32_bf16(av1, bv1, acc.a[1][1], 0, 0, 0);
  }
#pragma unroll
  for (int mi = 0; mi < 2; mi++)
#pragma unroll
    for (int ni = 0; ni < 2; ni++)
#pragma unroll
      for (int i = 0; i < 4; i++) {
        int row = row0 + mi * 16 + g * 4 + i;
        int col = cb + ni * 16 + l15;
        p.X[(size_t)row * HD + col] = f2b(acc.a[mi][ni][i] + p.binp[col]);
      }
}

// gxc0 for t=0: X[0:128] @ [Wxg0|Wxc0] -> gxc0a [128][3072].  grid 96.
__global__ __launch_bounds__(256) void k_gxc0init(Params p) {
  int blk = blockIdx.x;
  int w = threadIdx.x >> 6, lane = threadIdx.x & 63, l15 = lane & 15, g = lane >> 4;
  int row0 = w * 32, cb = blk * 32;
  Acc22 acc;
  gemm_wave(p.X, HD, p.WXC0T, HD, row0, cb, HD, acc);
#pragma unroll
  for (int mi = 0; mi < 2; mi++)
#pragma unroll
    for (int ni = 0; ni < 2; ni++)
#pragma unroll
      for (int i = 0; i < 4; i++) {
        int row = row0 + mi * 16 + g * 4 + i;
        int col = cb + ni * 16 + l15;
        p.gxc0a[row * 3072 + col] = acc.a[mi][ni][i];
      }
}

// ---------- persistent recurrence ----------
// 256 blocks x 512 threads; 8 waves/block; each wave owns rows w*16..w*16+15.
// P1(s): blk<128: pair {gx1[s-1] col cb, gh1[s-1] col cb} -> gate epi (rh1,u1)
//        blk>=128: gh0[s] col (blk-128)*16 -> gate epi (rh0,u0)
//        blk in [128,192): also cx1[s-1] col 2048+(blk-128)*16 (raw store)
// P2(s): blk<64:   ch0[s] -> h0[s];  + prefetch gxc0[s+1] tile 128+blk
//        blk<128:  ch1[s-1] -> h1[s-1], OUT[s-1]
//        blk>=128: prefetch gxc0[s+1] tile blk-128
__global__ __launch_bounds__(512, 2) void k_recur(Params p, int* bar) {
  const int blk = blockIdx.x;
  const int tid = threadIdx.x;
  const int w = tid >> 6, lane = tid & 63, l15 = lane & 15, g = lane >> 4;
  const int arow = w * 16 + l15;      // A-operand row for this lane
  const int g8 = g * 8;
  const int rbase = w * 16 + g * 4;   // C rows rbase..rbase+3

  for (int s = 0; s <= T_SEQ; ++s) {
    const float* gxc_s = (s & 1) ? p.gxc0b : p.gxc0a;
    // -------- P1 --------
    if (blk < 128) {
      if (s >= 1) {
        int cb = blk * 16;
        f32x4 x1 = tile16(p.h0b, p.WXC1T, cb, arow, l15, g8);      // gx1[s-1]
        f32x4 h1g = tile16(p.h1b, p.WhgT1, cb, arow, l15, g8);     // gh1[s-1]
        int c = cb + l15;
#pragma unroll
        for (int i = 0; i < 4; ++i) {
          int r = rbase + i;
          float gv = sigm(p.ag[2048 + c] * x1[i] * h1g[i] + p.b1g[2048 + c] * x1[i] +
                          p.b2g[2048 + c] * h1g[i] + p.bg[2048 + c]);
          if (c < HD) p.rh1b[r * HD + c] = f2b(gv * p.h1f[r * HD + c]);
          else        p.u1[r * HD + c - HD] = gv;
        }
      }
    } else {
      if (s < T_SEQ) {
        int cb = (blk - 128) * 16;
        f32x4 gh = tile16(p.h0b, p.WhgT0, cb, arow, l15, g8);      // gh0[s]
        int c = cb + l15;
#pragma unroll
        for (int i = 0; i < 4; ++i) {
          int r = rbase + i;
          float gx = gxc_s[r * 3072 + c];
          float gv = sigm(p.ag[c] * gx * gh[i] + p.b1g[c] * gx +
                          p.b2g[c] * gh[i] + p.bg[c]);
          if (c < HD) p.rh0b[r * HD + c] = f2b(gv * p.h0f[r * HD + c]);
          else        p.u0[r * HD + c - HD] = gv;
        }
      }
      if (blk < 192 && s >= 1) {
        int cb2 = (blk - 128) * 16;
        f32x4 cx = tile16(p.h0b, p.WXC1T, 2048 + cb2, arow, l15, g8);  // cx1[s-1]
        int c = cb2 + l15;
#pragma unroll
        for (int i = 0; i < 4; ++i) p.cx1[(rbase + i) * HD + c] = cx[i];
      }
    }
    gbar(bar);
    // -------- P2 --------
    float* gxc_n = ((s + 1) & 1) ? p.gxc0b : p.gxc0a;
    if (blk < 64) {
      if (s < T_SEQ) {
        int cb = blk * 16;
        f32x4 ch = tile16(p.rh0b, p.WhcT0, cb, arow, l15, g8);     // ch0[s]
        int c = cb + l15;
#pragma unroll
        for (int i = 0; i < 4; ++i) {
          int r = rbase + i;
          float cx = gxc_s[r * 3072 + 2048 + c];
          float cv = tanhf(p.ac[c] * cx * ch[i] + p.b1c[c] * cx +
                           p.b2c[c] * ch[i] + p.bc[c]);
          float un = p.u0[r * HD + c];
          float hn = un * p.h0f[r * HD + c] + (1.f - un) * cv;
          p.h0f[r * HD + c] = hn;
          p.h0b[r * HD + c] = f2b(hn);
        }
      }
      if (s + 1 < T_SEQ) {
        int cb = (128 + blk) * 16;
        f32x4 v = tile16(p.X + (size_t)(s + 1) * BATCH * HD, p.WXC0T, cb, arow, l15, g8);
#pragma unroll
        for (int i = 0; i < 4; ++i) gxc_n[(rbase + i) * 3072 + cb + l15] = v[i];
      }
    } else if (blk < 128) {
      if (s >= 1) {
        int cb = (blk - 64) * 16;
        f32x4 ch = tile16(p.rh1b, p.WhcT1, cb, arow, l15, g8);     // ch1[s-1]
        int c = cb + l15;
#pragma unroll
        for (int i = 0; i < 4; ++i) {
          int r = rbase + i;
          float cx = p.cx1[r * HD + c];
          float cv = tanhf(p.ac[HD + c] * cx * ch[i] + p.b1c[HD + c] * cx +
                           p.b2c[HD + c] * ch[i] + p.bc[HD + c]);
          float un = p.u1[r * HD + c];
          float hn = un * p.h1f[r * HD + c] + (1.f - un) * cv;
          p.h1f[r * HD + c] = hn;
          p.h1b[r * HD + c] = f2b(hn);
          p.OUTb[((size_t)(s - 1) * BATCH + r) * HD + c] = f2b(hn);
        }
      }
    } else {
      if (s + 1 < T_SEQ) {
        int cb = (blk - 128) * 16;
        f32x4 v = tile16(p.X + (size_t)(s + 1) * BATCH * HD, p.WXC0T, cb, arow, l15, g8);
#pragma unroll
        for (int i = 0; i < 4; ++i) gxc_n[(rbase + i) * 3072 + cb + l15] = v[i];
      }
    }
    gbar(bar);
  }
}

// ---------- NCE ----------

__global__ __launch_bounds__(256) void k_nce_gemm(Params p) {
  int blk = blockIdx.x;
  int mt = blk >> 1, nt = blk & 1;
  int w = threadIdx.x >> 6, lane = threadIdx.x & 63, l15 = lane & 15, g = lane >> 4;
  int row0 = w * 32, cb = nt * 32;
  Acc22 acc;
  gemm_wave(p.OUTb + (size_t)mt * 128 * HD, HD, p.sampWT, HD, row0, cb, HD, acc);
#pragma unroll
  for (int mi = 0; mi < 2; mi++)
#pragma unroll
    for (int ni = 0; ni < 2; ni++)
#pragma unroll
      for (int i = 0; i < 4; i++) {
        int row = mt * 128 + row0 + mi * 16 + g * 4 + i;
        int col = cb + ni * 16 + l15;
        p.slog[(size_t)row * 64 + col] = acc.a[mi][ni][i] + p.sampb[col];
      }
}

__global__ __launch_bounds__(256) void k_loss(Params p) {
  __shared__ float acc4[4];
  int w = threadIdx.x >> 6, lane = threadIdx.x & 63;
  int r = blockIdx.x * 4 + w;            // flatten order [b][t]
  int b = r >> 8, t = r & 255;
  int q = t * BATCH + b;                 // OUT row order [t][b]
  int label = p.tgt[r];
  const short* orow = p.OUTb + (size_t)q * HD;
  const float4* t4 = (const float4*)(p.smw + (size_t)label * HD) + lane * 4;
  float s = 0.f;
  const short8v* o8 = (const short8v*)(orow + lane * 16);
#pragma unroll
  for (int u2 = 0; u2 < 2; u2++) {
    short8v ov = o8[u2];
    float4 ta = t4[u2 * 2], tb = t4[u2 * 2 + 1];
    s += b2f(ov[0]) * ta.x + b2f(ov[1]) * ta.y + b2f(ov[2]) * ta.z + b2f(ov[3]) * ta.w;
    s += b2f(ov[4]) * tb.x + b2f(ov[5]) * tb.y + b2f(ov[6]) * tb.z + b2f(ov[7]) * tb.w;
  }
  for (int off = 32; off; off >>= 1) s += __shfl_down(s, off);
  float tl = __shfl(s, 0) + p.smb[label];
  float sl = p.slog[(size_t)q * 64 + lane];
  float v = splus(sl);
  for (int off = 32; off; off >>= 1) v += __shfl_down(v, off);
  if (lane == 0) acc4[w] = v + splus(-tl);
  __syncthreads();
  if (threadIdx.x == 0)
    atomicAdd(p.dout, (acc4[0] + acc4[1] + acc4[2] + acc4[3]) * (1.f / 32768.f));
}

// ---------- host ----------

extern "C" void kernel_launch(void* const* d_in, const int* in_sizes, int n_in,
                              void* d_out, int out_size, void* d_ws, size_t ws_size,
                              hipStream_t stream) {
  Params p;
  p.tok = (const int*)d_in[0];
  p.tgt = (const int*)d_in[1];
  p.nce = (const int*)d_in[2];
  p.emb = (const float*)d_in[3];
  p.win = (const float*)d_in[4];
  p.binp = (const float*)d_in[5];
  const float* Wxg = (const float*)d_in[6];
  const float* Whg = (const float*)d_in[7];
  p.ag = (const float*)d_in[8];
  p.b1g = (const float*)d_in[9];
  p.b2g = (const float*)d_in[10];
  p.bg = (const float*)d_in[11];
  const float* Wxc = (const float*)d_in[12];
  const float* Whc = (const float*)d_in[13];
  p.ac = (const float*)d_in[14];
  p.b1c = (const float*)d_in[15];
  p.b2c = (const float*)d_in[16];
  p.bc = (const float*)d_in[17];
  p.smw = (const float*)d_in[18];
  p.smb = (const float*)d_in[19];
  p.dout = (float*)d_out;

  char* w = (char*)d_ws;
  size_t off = 0;
  auto alloc = [&](size_t bytes) -> void* {
    void* q = w + off;
    off += (bytes + 255) & ~(size_t)255;
    return q;
  };
  p.embB   = (short*)alloc((size_t)16384 * 256 * 2);
  p.winT   = (short*)alloc((size_t)1024 * 256 * 2);
  p.WhgT0  = (short*)alloc((size_t)2048 * 1024 * 2);
  p.WhgT1  = (short*)alloc((size_t)2048 * 1024 * 2);
  p.WhcT0  = (short*)alloc((size_t)1024 * 1024 * 2);
  p.WhcT1  = (short*)alloc((size_t)1024 * 1024 * 2);
  p.WXC0T  = (short*)alloc((size_t)3072 * 1024 * 2);
  p.WXC1T  = (short*)alloc((size_t)3072 * 1024 * 2);
  p.sampWT = (short*)alloc((size_t)64 * 1024 * 2);
  p.sampb  = (float*)alloc(64 * 4);
  p.X      = (short*)alloc((size_t)32768 * 1024 * 2);
  p.OUTb   = (short*)alloc((size_t)32768 * 1024 * 2);
  p.h0f    = (float*)alloc((size_t)BATCH * HD * 4);   // h0f..h1b contiguous (zeroed together)
  p.h1f    = (float*)alloc((size_t)BATCH * HD * 4);
  p.h0b    = (short*)alloc((size_t)BATCH * HD * 2);
  p.h1b    = (short*)alloc((size_t)BATCH * HD * 2);
  p.rh0b   = (short*)alloc((size_t)BATCH * HD * 2);
  p.rh1b   = (short*)alloc((size_t)BATCH * HD * 2);
  p.u0     = (float*)alloc((size_t)BATCH * HD * 4);
  p.u1     = (float*)alloc((size_t)BATCH * HD * 4);
  p.cx1    = (float*)alloc((size_t)BATCH * HD * 4);
  p.gxc0a  = (float*)alloc((size_t)BATCH * 3072 * 4);
  p.gxc0b  = (float*)alloc((size_t)BATCH * 3072 * 4);
  p.slog   = (float*)alloc((size_t)32768 * 64 * 4);
  int* bar = (int*)alloc(8192);

  // zero h state (h0f,h1f fp32 + h0b,h1b bf16 = 393216 4B-words) + barrier + d_out
  k_zero<<<1536, 256, 0, stream>>>(p.h0f, 393216, p.dout, bar);
  // fp32 -> bf16 conversion (embedding only)
  k_conv<<<4096, 256, 0, stream>>>(p.emb, p.embB, 16384 * 256);
  // weight transposes (W [K][N] fp32 -> WT [N][K] bf16)
  dim3 tb(32, 8);
  k_transpose<<<dim3(32, 8),  tb, 0, stream>>>(p.win, p.winT, 256, 1024);
  k_transpose<<<dim3(64, 32), tb, 0, stream>>>(Whg, p.WhgT0, 1024, 2048);
  k_transpose<<<dim3(64, 32), tb, 0, stream>>>(Whg + (size_t)1024 * 2048, p.WhgT1, 1024, 2048);
  k_transpose<<<dim3(32, 32), tb, 0, stream>>>(Whc, p.WhcT0, 1024, 1024);
  k_transpose<<<dim3(32, 32), tb, 0, stream>>>(Whc + (size_t)1024 * 1024, p.WhcT1, 1024, 1024);
  k_transpose<<<dim3(64, 32), tb, 0, stream>>>(Wxg, p.WXC0T, 1024, 2048);
  k_transpose<<<dim3(32, 32), tb, 0, stream>>>(Wxc, p.WXC0T + (size_t)2048 * 1024, 1024, 1024);
  k_transpose<<<dim3(64, 32), tb, 0, stream>>>(Wxg + (size_t)1024 * 2048, p.WXC1T, 1024, 2048);
  k_transpose<<<dim3(32, 32), tb, 0, stream>>>(Wxc + (size_t)1024 * 1024, p.WXC1T + (size_t)2048 * 1024, 1024, 1024);
  // NCE sample weights
  k_sampw<<<64, 256, 0, stream>>>(p);
  // X = emb_gather @ win + bin  (layout [t][b][:])
  k_xproj<<<8192, 256, 0, stream>>>(p);
  // gxc0 for t=0
  k_gxc0init<<<96, 256, 0, stream>>>(p);

  // persistent recurrence (replaces 1024 dispatches)
  k_recur<<<NBLK, 512, 0, stream>>>(p, bar);

  // NCE tail
  k_nce_gemm<<<512, 256, 0, stream>>>(p);
  k_loss<<<8192, 256, 0, stream>>>(p);
}

// Round 7
// 52214.508 us; speedup vs baseline: 1.0207x; 1.0207x over previous
//
#include <hip/hip_runtime.h>
#include <hip/hip_bf16.h>

// CharRNN (MI-GRU x2, T=256, B=128, H=1024) + NCE loss.
// Round 7 (= audited round 6 + defensive dyn-LDS attribute):
// persistent recurrence + LDS-PINNED WEIGHTS.
// Round-5 post-mortem: device-scope fences in the grid barrier invalidate per-XCD
// L2 every phase -> 24MB of weights re-fetched per step (5.5GB/dispatch, 102us/phase).
// Fix: 768 weight slices (16 cols x 1024 K x bf16 = 32KB) pinned in LDS, 3 per block
// (96KB dynamic LDS, 1 block/CU, exact 256-block co-residency). LDS is immune to the
// coherence invalidations. Barrier + epilogue math identical to the passing round 5.

#define T_SEQ 256
#define BATCH 128
#define HD    1024
#define NBLK  256

typedef __attribute__((ext_vector_type(8))) short short8v;
typedef __attribute__((ext_vector_type(4))) float f32x4;

static __device__ __forceinline__ short f2b(float v) {
  __hip_bfloat16 h = __float2bfloat16(v);
  return __builtin_bit_cast(short, h);
}
static __device__ __forceinline__ float b2f(short s) {
  return __bfloat162float(__builtin_bit_cast(__hip_bfloat16, s));
}
static __device__ __forceinline__ float sigm(float x) { return 1.f / (1.f + __expf(-x)); }
static __device__ __forceinline__ float splus(float x) {
  return fmaxf(x, 0.f) + log1pf(__expf(-fabsf(x)));
}

struct Acc22 { f32x4 a[2][2]; };

// ---- 32x32-tile wave GEMM (setup + NCE kernels; unchanged) ----
static __device__ __forceinline__ void gemm_wave(
    const short* __restrict__ A, int lda, const short* __restrict__ WT, int ldk,
    int row0, int cb, int K, Acc22& o) {
  const int lane = threadIdx.x & 63;
  const int l15 = lane & 15, g = lane >> 4;
  f32x4 z = {0.f, 0.f, 0.f, 0.f};
  o.a[0][0] = z; o.a[0][1] = z; o.a[1][0] = z; o.a[1][1] = z;
  const short* a0 = A + (size_t)(row0 + l15) * lda + g * 8;
  const short* a1 = a0 + 16 * (size_t)lda;
  const short* b0 = WT + (size_t)(cb + l15) * ldk + g * 8;
  const short* b1 = b0 + 16 * (size_t)ldk;
  for (int k = 0; k < K; k += 32) {
    short8v av0 = *(const short8v*)(a0 + k);
    short8v av1 = *(const short8v*)(a1 + k);
    short8v bv0 = *(const short8v*)(b0 + k);
    short8v bv1 = *(const short8v*)(b1 + k);
    o.a[0][0] = __builtin_amdgcn_mfma_f32_16x16x32_bf16(av0, bv0, o.a[0][0], 0, 0, 0);
    o.a[0][1] = __builtin_amdgcn_mfma_f32_16x16x32_bf16(av0, bv1, o.a[0][1], 0, 0, 0);
    o.a[1][0] = __builtin_amdgcn_mfma_f32_16x16x32_bf16(av1, bv0, o.a[1][0], 0, 0, 0);
    o.a[1][1] = __builtin_amdgcn_mfma_f32_16x16x32_bf16(av1, bv1, o.a[1][1], 0, 0, 0);
  }
}

struct Params {
  const int *tok, *tgt, *nce;
  const float *emb, *win, *binp;
  const float *ag, *b1g, *b2g, *bg, *ac, *b1c, *b2c, *bc;
  const float *smw, *smb;
  short *embB, *winT, *WhgT0, *WhgT1, *WhcT0, *WhcT1, *WXC0T, *WXC1T;
  short *sampWT;
  float *sampb;
  short *X, *OUTb;
  float *h0f, *h1f; short *h0b, *h1b;
  short *rh0b, *rh1b;
  float *u0, *u1, *cx1;
  float *gxc0a, *gxc0b;
  float *slog;
  float *dout;
};

// ---------- grid barrier (two-level; proven correct in round 5) ----------
static __device__ __forceinline__ void gbar(int* bar) {
  __syncthreads();
  if (threadIdx.x == 0) {
    __threadfence();
    int* rgen = bar + 64;
    int g0 = __hip_atomic_load(rgen, __ATOMIC_RELAXED, __HIP_MEMORY_SCOPE_AGENT);
    int* gcnt = bar + 128 + (blockIdx.x >> 4) * 64;
    if (__hip_atomic_fetch_add(gcnt, 1, __ATOMIC_ACQ_REL, __HIP_MEMORY_SCOPE_AGENT) == 15) {
      __hip_atomic_store(gcnt, 0, __ATOMIC_RELAXED, __HIP_MEMORY_SCOPE_AGENT);
      if (__hip_atomic_fetch_add(bar, 1, __ATOMIC_ACQ_REL, __HIP_MEMORY_SCOPE_AGENT) == 15) {
        __hip_atomic_store(bar, 0, __ATOMIC_RELAXED, __HIP_MEMORY_SCOPE_AGENT);
        __hip_atomic_store(rgen, g0 + 1, __ATOMIC_RELEASE, __HIP_MEMORY_SCOPE_AGENT);
      }
    }
    while (__hip_atomic_load(rgen, __ATOMIC_ACQUIRE, __HIP_MEMORY_SCOPE_AGENT) == g0)
      __builtin_amdgcn_s_sleep(2);
  }
  __syncthreads();
  __threadfence();
}

// ---------- setup kernels (unchanged) ----------

__global__ void k_zero(float* __restrict__ p, int n, float* __restrict__ dout,
                       int* __restrict__ bar) {
  int i = blockIdx.x * 256 + threadIdx.x;
  if (i < n) p[i] = 0.f;
  if (blockIdx.x == 0) {
    for (int j = threadIdx.x; j < 2048; j += 256) bar[j] = 0;
    if (threadIdx.x == 0) *dout = 0.f;
  }
}

__global__ void k_conv(const float* __restrict__ s, short* __restrict__ d, int n) {
  int i = (blockIdx.x * 256 + threadIdx.x) * 4;
  if (i + 4 <= n) {
    float4 v = *(const float4*)(s + i);
    d[i] = f2b(v.x); d[i + 1] = f2b(v.y); d[i + 2] = f2b(v.z); d[i + 3] = f2b(v.w);
  }
}

__global__ void k_transpose(const float* __restrict__ W, short* __restrict__ WT,
                            int K, int N) {
  __shared__ short tile[32][33];
  int nt = blockIdx.x, kt = blockIdx.y;
  int tx = threadIdx.x, ty = threadIdx.y;
#pragma unroll
  for (int r = 0; r < 4; r++) {
    int k = kt * 32 + ty + r * 8;
    int n = nt * 32 + tx;
    tile[ty + r * 8][tx] = f2b(W[(size_t)k * N + n]);
  }
  __syncthreads();
#pragma unroll
  for (int r = 0; r < 4; r++) {
    int n = nt * 32 + ty + r * 8;
    int k = kt * 32 + tx;
    WT[(size_t)n * K + k] = tile[tx][ty + r * 8];
  }
}

__global__ void k_sampw(Params p) {
  int s = blockIdx.x;
  int row = p.nce[s];
  for (int j = threadIdx.x; j < HD; j += 256)
    p.sampWT[s * HD + j] = f2b(p.smw[(size_t)row * HD + j]);
  if (threadIdx.x == 0) p.sampb[s] = p.smb[row];
}

__global__ __launch_bounds__(256) void k_xproj(Params p) {
  int blk = blockIdx.x;
  int mt = blk >> 5, nt = blk & 31;
  int w = threadIdx.x >> 6, lane = threadIdx.x & 63, l15 = lane & 15, g = lane >> 4;
  int row0 = mt * 128 + w * 32, cb = nt * 32;
  const short* ap[2];
#pragma unroll
  for (int mi = 0; mi < 2; mi++) {
    int r = row0 + mi * 16 + l15;
    int tt = r >> 7, bb = r & 127;
    int tk = p.tok[bb * T_SEQ + tt];
    ap[mi] = p.embB + (size_t)tk * 256 + g * 8;
  }
  f32x4 z = {0.f, 0.f, 0.f, 0.f};
  Acc22 acc; acc.a[0][0] = z; acc.a[0][1] = z; acc.a[1][0] = z; acc.a[1][1] = z;
  const short* b0 = p.winT + (size_t)(cb + l15) * 256 + g * 8;
  const short* b1 = b0 + 16 * 256;
  for (int k = 0; k < 256; k += 32) {
    short8v av0 = *(const short8v*)(ap[0] + k);
    short8v av1 = *(const short8v*)(ap[1] + k);
    short8v bv0 = *(const short8v*)(b0 + k);
    short8v bv1 = *(const short8v*)(b1 + k);
    acc.a[0][0] = __builtin_amdgcn_mfma_f32_16x16x32_bf16(av0, bv0, acc.a[0][0], 0, 0, 0);
    acc.a[0][1] = __builtin_amdgcn_mfma_f32_16x16x32_bf16(av0, bv1, acc.a[0][1], 0, 0, 0);
    acc.a[1][0] = __builtin_amdgcn_mfma_f32_16x16x32_bf16(av1, bv0, acc.a[1][0], 0, 0, 0);
    acc.a[1][1] = __builtin_amdgcn_mfma_f32_16x16x32_bf16(av1, bv1, acc.a[1][1], 0, 0, 0);
  }
#pragma unroll
  for (int mi = 0; mi < 2; mi++)
#pragma unroll
    for (int ni = 0; ni < 2; ni++)
#pragma unroll
      for (int i = 0; i < 4; i++) {
        int row = row0 + mi * 16 + g * 4 + i;
        int col = cb + ni * 16 + l15;
        p.X[(size_t)row * HD + col] = f2b(acc.a[mi][ni][i] + p.binp[col]);
      }
}

__global__ __launch_bounds__(256) void k_gxc0init(Params p) {
  int blk = blockIdx.x;
  int w = threadIdx.x >> 6, lane = threadIdx.x & 63, l15 = lane & 15, g = lane >> 4;
  int row0 = w * 32, cb = blk * 32;
  Acc22 acc;
  gemm_wave(p.X, HD, p.WXC0T, HD, row0, cb, HD, acc);
#pragma unroll
  for (int mi = 0; mi < 2; mi++)
#pragma unroll
    for (int ni = 0; ni < 2; ni++)
#pragma unroll
      for (int i = 0; i < 4; i++) {
        int row = row0 + mi * 16 + g * 4 + i;
        int col = cb + ni * 16 + l15;
        p.gxc0a[row * 3072 + col] = acc.a[mi][ni][i];
      }
}

// ---------- persistent recurrence with LDS-pinned weights ----------
// 256 blocks x 512 threads, 96KB dynamic LDS = 3 slices of [16 cols][1024 K] bf16.
// Slice layout in LDS: short idx = slot*16384 + col*1024 + (k ^ ((col&7)<<3))
// (XOR swizzle -> ds_read_b128 spreads rows across banks).
// Roles:
//  blk 0..127  : P1 = gx1+gh1 pair (slots 0,1 = WXC1T[blk], WhgT1[blk]) -> gate1 epi
//                P2 = blk<64 ? ch0 (slot2=WhcT0[blk]) : ch1 (slot2=WhcT1[blk-64])
//  blk 128..191: P1 = gh0 x2 (slots 0,1 = WhgT0[2b],[2b+1]) -> gate0 epi
//                P2 = gxc0-prefetch (slot2 = WXC0T[b])
//  blk 192..255: P1 = cx1 (slot0 = WXC1T cols 2048+16b) -> raw store
//                P2 = gxc0-prefetch x2 (slots 1,2 = WXC0T[64+2b],[65+2b])

extern __shared__ short wlds[];

static __device__ __forceinline__ f32x4 tile16_lds(const short* __restrict__ A,
    int slot, int arow, int l15, int g8) {
  f32x4 acc = {0.f, 0.f, 0.f, 0.f};
  const short* ap = A + (size_t)arow * HD + g8;
  const int xoff = (l15 & 7) << 3;
  const int bbase = slot * 16384 + l15 * 1024;
#pragma unroll 8
  for (int ks = 0; ks < 32; ++ks) {
    short8v av = *(const short8v*)(ap + ks * 32);
    short8v bv = *(const short8v*)&wlds[bbase + ((g8 + ks * 32) ^ xoff)];
    acc = __builtin_amdgcn_mfma_f32_16x16x32_bf16(av, bv, acc, 0, 0, 0);
  }
  return acc;
}

__global__ __launch_bounds__(512, 2) void k_recur(Params p, int* bar) {
  const int blk = blockIdx.x;
  const int tid = threadIdx.x;
  const int w = tid >> 6, lane = tid & 63, l15 = lane & 15, g = lane >> 4;
  const int arow = w * 16 + l15;
  const int g8 = g * 8;
  const int rbase = w * 16 + g * 4;

  // slice sources
  const short* src[3];
  int ct1, ct2;
  if (blk < 128) {
    ct1 = blk;
    src[0] = p.WXC1T + (size_t)blk * 16 * HD;
    src[1] = p.WhgT1 + (size_t)blk * 16 * HD;
    if (blk < 64) { ct2 = blk;       src[2] = p.WhcT0 + (size_t)ct2 * 16 * HD; }
    else          { ct2 = blk - 64;  src[2] = p.WhcT1 + (size_t)ct2 * 16 * HD; }
  } else if (blk < 192) {
    int b = blk - 128; ct1 = 2 * b; ct2 = b;
    src[0] = p.WhgT0 + (size_t)(2 * b) * 16 * HD;
    src[1] = p.WhgT0 + (size_t)(2 * b + 1) * 16 * HD;
    src[2] = p.WXC0T + (size_t)b * 16 * HD;
  } else {
    int b = blk - 192; ct1 = b; ct2 = 64 + 2 * b;
    src[0] = p.WXC1T + ((size_t)2048 + b * 16) * HD;
    src[1] = p.WXC0T + (size_t)(64 + 2 * b) * 16 * HD;
    src[2] = p.WXC0T + (size_t)(65 + 2 * b) * 16 * HD;
  }
  // preload 3 x 32KB with XOR swizzle
#pragma unroll
  for (int slot = 0; slot < 3; ++slot) {
    const short* s0 = src[slot];
    for (int j = tid; j < 2048; j += 512) {
      int col = j >> 7, k = (j & 127) * 8;
      short8v v = *(const short8v*)(s0 + col * HD + k);
      *(short8v*)&wlds[slot * 16384 + col * 1024 + (k ^ ((col & 7) << 3))] = v;
    }
  }
  __syncthreads();

  for (int s = 0; s <= T_SEQ; ++s) {
    const float* gxc_s = (s & 1) ? p.gxc0b : p.gxc0a;
    // -------- P1 --------
    if (blk < 128) {
      if (s >= 1) {
        f32x4 x1 = tile16_lds(p.h0b, 0, arow, l15, g8);       // gx1[s-1]
        f32x4 h1g = tile16_lds(p.h1b, 1, arow, l15, g8);      // gh1[s-1]
        int c = ct1 * 16 + l15;
#pragma unroll
        for (int i = 0; i < 4; ++i) {
          int r = rbase + i;
          float gv = sigm(p.ag[2048 + c] * x1[i] * h1g[i] + p.b1g[2048 + c] * x1[i] +
                          p.b2g[2048 + c] * h1g[i] + p.bg[2048 + c]);
          if (c < HD) p.rh1b[r * HD + c] = f2b(gv * p.h1f[r * HD + c]);
          else        p.u1[r * HD + c - HD] = gv;
        }
      }
    } else if (blk < 192) {
      if (s < T_SEQ) {
#pragma unroll
        for (int sl = 0; sl < 2; ++sl) {
          f32x4 gh = tile16_lds(p.h0b, sl, arow, l15, g8);    // gh0[s]
          int c = (ct1 + sl) * 16 + l15;
#pragma unroll
          for (int i = 0; i < 4; ++i) {
            int r = rbase + i;
            float gx = gxc_s[r * 3072 + c];
            float gv = sigm(p.ag[c] * gx * gh[i] + p.b1g[c] * gx +
                            p.b2g[c] * gh[i] + p.bg[c]);
            if (c < HD) p.rh0b[r * HD + c] = f2b(gv * p.h0f[r * HD + c]);
            else        p.u0[r * HD + c - HD] = gv;
          }
        }
      }
    } else {
      if (s >= 1) {
        f32x4 cx = tile16_lds(p.h0b, 0, arow, l15, g8);       // cx1[s-1]
        int c = ct1 * 16 + l15;
#pragma unroll
        for (int i = 0; i < 4; ++i) p.cx1[(rbase + i) * HD + c] = cx[i];
      }
    }
    gbar(bar);
    // -------- P2 --------
    float* gxc_n = ((s + 1) & 1) ? p.gxc0b : p.gxc0a;
    if (blk < 64) {
      if (s < T_SEQ) {
        f32x4 ch = tile16_lds(p.rh0b, 2, arow, l15, g8);      // ch0[s]
        int c = ct2 * 16 + l15;
#pragma unroll
        for (int i = 0; i < 4; ++i) {
          int r = rbase + i;
          float cx = gxc_s[r * 3072 + 2048 + c];
          float cv = tanhf(p.ac[c] * cx * ch[i] + p.b1c[c] * cx +
                           p.b2c[c] * ch[i] + p.bc[c]);
          float un = p.u0[r * HD + c];
          float hn = un * p.h0f[r * HD + c] + (1.f - un) * cv;
          p.h0f[r * HD + c] = hn;
          p.h0b[r * HD + c] = f2b(hn);
        }
      }
    } else if (blk < 128) {
      if (s >= 1) {
        f32x4 ch = tile16_lds(p.rh1b, 2, arow, l15, g8);      // ch1[s-1]
        int c = ct2 * 16 + l15;
#pragma unroll
        for (int i = 0; i < 4; ++i) {
          int r = rbase + i;
          float cx = p.cx1[r * HD + c];
          float cv = tanhf(p.ac[HD + c] * cx * ch[i] + p.b1c[HD + c] * cx +
                           p.b2c[HD + c] * ch[i] + p.bc[HD + c]);
          float un = p.u1[r * HD + c];
          float hn = un * p.h1f[r * HD + c] + (1.f - un) * cv;
          p.h1f[r * HD + c] = hn;
          p.h1b[r * HD + c] = f2b(hn);
          p.OUTb[((size_t)(s - 1) * BATCH + r) * HD + c] = f2b(hn);
        }
      }
    } else if (blk < 192) {
      if (s + 1 < T_SEQ) {
        const short* A = p.X + (size_t)(s + 1) * BATCH * HD;
        f32x4 v = tile16_lds(A, 2, arow, l15, g8);            // gxc0[s+1] cols 0..1023
        int c = ct2 * 16 + l15;
#pragma unroll
        for (int i = 0; i < 4; ++i) gxc_n[(rbase + i) * 3072 + c] = v[i];
      }
    } else {
      if (s + 1 < T_SEQ) {
        const short* A = p.X + (size_t)(s + 1) * BATCH * HD;
#pragma unroll
        for (int sl = 0; sl < 2; ++sl) {
          f32x4 v = tile16_lds(A, 1 + sl, arow, l15, g8);     // cols 1024..3071
          int c = (ct2 + sl) * 16 + l15;
#pragma unroll
          for (int i = 0; i < 4; ++i) gxc_n[(rbase + i) * 3072 + c] = v[i];
        }
      }
    }
    gbar(bar);
  }
}

// ---------- NCE (unchanged) ----------

__global__ __launch_bounds__(256) void k_nce_gemm(Params p) {
  int blk = blockIdx.x;
  int mt = blk >> 1, nt = blk & 1;
  int w = threadIdx.x >> 6, lane = threadIdx.x & 63, l15 = lane & 15, g = lane >> 4;
  int row0 = w * 32, cb = nt * 32;
  Acc22 acc;
  gemm_wave(p.OUTb + (size_t)mt * 128 * HD, HD, p.sampWT, HD, row0, cb, HD, acc);
#pragma unroll
  for (int mi = 0; mi < 2; mi++)
#pragma unroll
    for (int ni = 0; ni < 2; ni++)
#pragma unroll
      for (int i = 0; i < 4; i++) {
        int row = mt * 128 + row0 + mi * 16 + g * 4 + i;
        int col = cb + ni * 16 + l15;
        p.slog[(size_t)row * 64 + col] = acc.a[mi][ni][i] + p.sampb[col];
      }
}

__global__ __launch_bounds__(256) void k_loss(Params p) {
  __shared__ float acc4[4];
  int w = threadIdx.x >> 6, lane = threadIdx.x & 63;
  int r = blockIdx.x * 4 + w;
  int b = r >> 8, t = r & 255;
  int q = t * BATCH + b;
  int label = p.tgt[r];
  const short* orow = p.OUTb + (size_t)q * HD;
  const float4* t4 = (const float4*)(p.smw + (size_t)label * HD) + lane * 4;
  float s = 0.f;
  const short8v* o8 = (const short8v*)(orow + lane * 16);
#pragma unroll
  for (int u2 = 0; u2 < 2; u2++) {
    short8v ov = o8[u2];
    float4 ta = t4[u2 * 2], tb = t4[u2 * 2 + 1];
    s += b2f(ov[0]) * ta.x + b2f(ov[1]) * ta.y + b2f(ov[2]) * ta.z + b2f(ov[3]) * ta.w;
    s += b2f(ov[4]) * tb.x + b2f(ov[5]) * tb.y + b2f(ov[6]) * tb.z + b2f(ov[7]) * tb.w;
  }
  for (int off = 32; off; off >>= 1) s += __shfl_down(s, off);
  float tl = __shfl(s, 0) + p.smb[label];
  float sl = p.slog[(size_t)q * 64 + lane];
  float v = splus(sl);
  for (int off = 32; off; off >>= 1) v += __shfl_down(v, off);
  if (lane == 0) acc4[w] = v + splus(-tl);
  __syncthreads();
  if (threadIdx.x == 0)
    atomicAdd(p.dout, (acc4[0] + acc4[1] + acc4[2] + acc4[3]) * (1.f / 32768.f));
}

// ---------- host ----------

extern "C" void kernel_launch(void* const* d_in, const int* in_sizes, int n_in,
                              void* d_out, int out_size, void* d_ws, size_t ws_size,
                              hipStream_t stream) {
  Params p;
  p.tok = (const int*)d_in[0];
  p.tgt = (const int*)d_in[1];
  p.nce = (const int*)d_in[2];
  p.emb = (const float*)d_in[3];
  p.win = (const float*)d_in[4];
  p.binp = (const float*)d_in[5];
  const float* Wxg = (const float*)d_in[6];
  const float* Whg = (const float*)d_in[7];
  p.ag = (const float*)d_in[8];
  p.b1g = (const float*)d_in[9];
  p.b2g = (const float*)d_in[10];
  p.bg = (const float*)d_in[11];
  const float* Wxc = (const float*)d_in[12];
  const float* Whc = (const float*)d_in[13];
  p.ac = (const float*)d_in[14];
  p.b1c = (const float*)d_in[15];
  p.b2c = (const float*)d_in[16];
  p.bc = (const float*)d_in[17];
  p.smw = (const float*)d_in[18];
  p.smb = (const float*)d_in[19];
  p.dout = (float*)d_out;

  char* w = (char*)d_ws;
  size_t off = 0;
  auto alloc = [&](size_t bytes) -> void* {
    void* q = w + off;
    off += (bytes + 255) & ~(size_t)255;
    return q;
  };
  p.embB   = (short*)alloc((size_t)16384 * 256 * 2);
  p.winT   = (short*)alloc((size_t)1024 * 256 * 2);
  p.WhgT0  = (short*)alloc((size_t)2048 * 1024 * 2);
  p.WhgT1  = (short*)alloc((size_t)2048 * 1024 * 2);
  p.WhcT0  = (short*)alloc((size_t)1024 * 1024 * 2);
  p.WhcT1  = (short*)alloc((size_t)1024 * 1024 * 2);
  p.WXC0T  = (short*)alloc((size_t)3072 * 1024 * 2);
  p.WXC1T  = (short*)alloc((size_t)3072 * 1024 * 2);
  p.sampWT = (short*)alloc((size_t)64 * 1024 * 2);
  p.sampb  = (float*)alloc(64 * 4);
  p.X      = (short*)alloc((size_t)32768 * 1024 * 2);
  p.OUTb   = (short*)alloc((size_t)32768 * 1024 * 2);
  p.h0f    = (float*)alloc((size_t)BATCH * HD * 4);   // h0f..h1b contiguous (zeroed together)
  p.h1f    = (float*)alloc((size_t)BATCH * HD * 4);
  p.h0b    = (short*)alloc((size_t)BATCH * HD * 2);
  p.h1b    = (short*)alloc((size_t)BATCH * HD * 2);
  p.rh0b   = (short*)alloc((size_t)BATCH * HD * 2);
  p.rh1b   = (short*)alloc((size_t)BATCH * HD * 2);
  p.u0     = (float*)alloc((size_t)BATCH * HD * 4);
  p.u1     = (float*)alloc((size_t)BATCH * HD * 4);
  p.cx1    = (float*)alloc((size_t)BATCH * HD * 4);
  p.gxc0a  = (float*)alloc((size_t)BATCH * 3072 * 4);
  p.gxc0b  = (float*)alloc((size_t)BATCH * 3072 * 4);
  p.slog   = (float*)alloc((size_t)32768 * 64 * 4);
  int* bar = (int*)alloc(8192);

  // allow >64KB dynamic LDS for k_recur (idempotent; host-side, capture-safe)
  static bool attr_set = false;
  if (!attr_set) {
    hipFuncSetAttribute((const void*)k_recur,
                        hipFuncAttributeMaxDynamicSharedMemorySize, 98304);
    attr_set = true;
  }

  // zero h state + barrier + d_out
  k_zero<<<1536, 256, 0, stream>>>(p.h0f, 393216, p.dout, bar);
  // fp32 -> bf16 conversion (embedding only)
  k_conv<<<4096, 256, 0, stream>>>(p.emb, p.embB, 16384 * 256);
  // weight transposes (W [K][N] fp32 -> WT [N][K] bf16)
  dim3 tb(32, 8);
  k_transpose<<<dim3(32, 8),  tb, 0, stream>>>(p.win, p.winT, 256, 1024);
  k_transpose<<<dim3(64, 32), tb, 0, stream>>>(Whg, p.WhgT0, 1024, 2048);
  k_transpose<<<dim3(64, 32), tb, 0, stream>>>(Whg + (size_t)1024 * 2048, p.WhgT1, 1024, 2048);
  k_transpose<<<dim3(32, 32), tb, 0, stream>>>(Whc, p.WhcT0, 1024, 1024);
  k_transpose<<<dim3(32, 32), tb, 0, stream>>>(Whc + (size_t)1024 * 1024, p.WhcT1, 1024, 1024);
  k_transpose<<<dim3(64, 32), tb, 0, stream>>>(Wxg, p.WXC0T, 1024, 2048);
  k_transpose<<<dim3(32, 32), tb, 0, stream>>>(Wxc, p.WXC0T + (size_t)2048 * 1024, 1024, 1024);
  k_transpose<<<dim3(64, 32), tb, 0, stream>>>(Wxg + (size_t)1024 * 2048, p.WXC1T, 1024, 2048);
  k_transpose<<<dim3(32, 32), tb, 0, stream>>>(Wxc + (size_t)1024 * 1024, p.WXC1T + (size_t)2048 * 1024, 1024, 1024);
  // NCE sample weights
  k_sampw<<<64, 256, 0, stream>>>(p);
  // X = emb_gather @ win + bin  (layout [t][b][:])
  k_xproj<<<8192, 256, 0, stream>>>(p);
  // gxc0 for t=0
  k_gxc0init<<<96, 256, 0, stream>>>(p);

  // persistent recurrence with LDS-pinned weights (96KB dynamic LDS)
  k_recur<<<NBLK, 512, 98304, stream>>>(p, bar);

  // NCE tail
  k_nce_gemm<<<512, 256, 0, stream>>>(p);
  k_loss<<<8192, 256, 0, stream>>>(p);
}

// Round 8
// 19198.109 us; speedup vs baseline: 2.7760x; 2.7198x over previous
//
#include <hip/hip_runtime.h>
#include <hip/hip_bf16.h>

// CharRNN (MI-GRU x2, T=256, B=128, H=1024) + NCE loss.
// Round 8: persistent recurrence + LDS-pinned weights + CHEAP GRID BARRIER.
// Round-7 post-mortem: time invariant (~100us/phase) across 2.5x FETCH change ->
// barrier-bound, not memory-bound. Old gbar did an agent-ACQUIRE load per poll
// iteration (L1/L2 invalidate each!) plus a per-thread trailing threadfence
// (512 invs/block/phase). New gbar: leader-only release fence on entry, RELAXED
// polling (agent atomics are sc1-coherent without invalidation), single leader
// acquire fence on exit. Everything else identical to passing round 7.

#define T_SEQ 256
#define BATCH 128
#define HD    1024
#define NBLK  256

typedef __attribute__((ext_vector_type(8))) short short8v;
typedef __attribute__((ext_vector_type(4))) float f32x4;

static __device__ __forceinline__ short f2b(float v) {
  __hip_bfloat16 h = __float2bfloat16(v);
  return __builtin_bit_cast(short, h);
}
static __device__ __forceinline__ float b2f(short s) {
  return __bfloat162float(__builtin_bit_cast(__hip_bfloat16, s));
}
static __device__ __forceinline__ float sigm(float x) { return 1.f / (1.f + __expf(-x)); }
static __device__ __forceinline__ float splus(float x) {
  return fmaxf(x, 0.f) + log1pf(__expf(-fabsf(x)));
}

struct Acc22 { f32x4 a[2][2]; };

// ---- 32x32-tile wave GEMM (setup + NCE kernels; unchanged) ----
static __device__ __forceinline__ void gemm_wave(
    const short* __restrict__ A, int lda, const short* __restrict__ WT, int ldk,
    int row0, int cb, int K, Acc22& o) {
  const int lane = threadIdx.x & 63;
  const int l15 = lane & 15, g = lane >> 4;
  f32x4 z = {0.f, 0.f, 0.f, 0.f};
  o.a[0][0] = z; o.a[0][1] = z; o.a[1][0] = z; o.a[1][1] = z;
  const short* a0 = A + (size_t)(row0 + l15) * lda + g * 8;
  const short* a1 = a0 + 16 * (size_t)lda;
  const short* b0 = WT + (size_t)(cb + l15) * ldk + g * 8;
  const short* b1 = b0 + 16 * (size_t)ldk;
  for (int k = 0; k < K; k += 32) {
    short8v av0 = *(const short8v*)(a0 + k);
    short8v av1 = *(const short8v*)(a1 + k);
    short8v bv0 = *(const short8v*)(b0 + k);
    short8v bv1 = *(const short8v*)(b1 + k);
    o.a[0][0] = __builtin_amdgcn_mfma_f32_16x16x32_bf16(av0, bv0, o.a[0][0], 0, 0, 0);
    o.a[0][1] = __builtin_amdgcn_mfma_f32_16x16x32_bf16(av0, bv1, o.a[0][1], 0, 0, 0);
    o.a[1][0] = __builtin_amdgcn_mfma_f32_16x16x32_bf16(av1, bv0, o.a[1][0], 0, 0, 0);
    o.a[1][1] = __builtin_amdgcn_mfma_f32_16x16x32_bf16(av1, bv1, o.a[1][1], 0, 0, 0);
  }
}

struct Params {
  const int *tok, *tgt, *nce;
  const float *emb, *win, *binp;
  const float *ag, *b1g, *b2g, *bg, *ac, *b1c, *b2c, *bc;
  const float *smw, *smb;
  short *embB, *winT, *WhgT0, *WhgT1, *WhcT0, *WhcT1, *WXC0T, *WXC1T;
  short *sampWT;
  float *sampb;
  short *X, *OUTb;
  float *h0f, *h1f; short *h0b, *h1b;
  short *rh0b, *rh1b;
  float *u0, *u1, *cx1;
  float *gxc0a, *gxc0b;
  float *slog;
  float *dout;
};

// ---------- grid barrier: leader-only fences, relaxed polling ----------
// bar[0]: root count; bar[64]: root generation; bar[128 + grp*64]: group counts.
static __device__ __forceinline__ void gbar(int* bar) {
  __syncthreads();   // all waves drained (compiler emits vmcnt(0) before s_barrier)
  if (threadIdx.x == 0) {
    __builtin_amdgcn_fence(__ATOMIC_RELEASE, "agent");   // publish block's writes (wb)
    int* rgen = bar + 64;
    int g0 = __hip_atomic_load(rgen, __ATOMIC_RELAXED, __HIP_MEMORY_SCOPE_AGENT);
    int* gcnt = bar + 128 + (blockIdx.x >> 4) * 64;
    if (__hip_atomic_fetch_add(gcnt, 1, __ATOMIC_ACQ_REL, __HIP_MEMORY_SCOPE_AGENT) == 15) {
      __hip_atomic_store(gcnt, 0, __ATOMIC_RELAXED, __HIP_MEMORY_SCOPE_AGENT);
      if (__hip_atomic_fetch_add(bar, 1, __ATOMIC_ACQ_REL, __HIP_MEMORY_SCOPE_AGENT) == 15) {
        __hip_atomic_store(bar, 0, __ATOMIC_RELAXED, __HIP_MEMORY_SCOPE_AGENT);
        __hip_atomic_store(rgen, g0 + 1, __ATOMIC_RELEASE, __HIP_MEMORY_SCOPE_AGENT);
      }
    }
    // RELAXED poll: agent-scope atomic loads are coherent (sc1) without
    // per-iteration cache invalidation. One acquire fence after wake.
    while (__hip_atomic_load(rgen, __ATOMIC_RELAXED, __HIP_MEMORY_SCOPE_AGENT) == g0)
      __builtin_amdgcn_s_sleep(2);
    __builtin_amdgcn_fence(__ATOMIC_ACQUIRE, "agent");   // inv L1 + XCD L2 once
  }
  __syncthreads();   // other waves' loads ordered after leader's acquire fence
}

// ---------- setup kernels (unchanged) ----------

__global__ void k_zero(float* __restrict__ p, int n, float* __restrict__ dout,
                       int* __restrict__ bar) {
  int i = blockIdx.x * 256 + threadIdx.x;
  if (i < n) p[i] = 0.f;
  if (blockIdx.x == 0) {
    for (int j = threadIdx.x; j < 2048; j += 256) bar[j] = 0;
    if (threadIdx.x == 0) *dout = 0.f;
  }
}

__global__ void k_conv(const float* __restrict__ s, short* __restrict__ d, int n) {
  int i = (blockIdx.x * 256 + threadIdx.x) * 4;
  if (i + 4 <= n) {
    float4 v = *(const float4*)(s + i);
    d[i] = f2b(v.x); d[i + 1] = f2b(v.y); d[i + 2] = f2b(v.z); d[i + 3] = f2b(v.w);
  }
}

__global__ void k_transpose(const float* __restrict__ W, short* __restrict__ WT,
                            int K, int N) {
  __shared__ short tile[32][33];
  int nt = blockIdx.x, kt = blockIdx.y;
  int tx = threadIdx.x, ty = threadIdx.y;
#pragma unroll
  for (int r = 0; r < 4; r++) {
    int k = kt * 32 + ty + r * 8;
    int n = nt * 32 + tx;
    tile[ty + r * 8][tx] = f2b(W[(size_t)k * N + n]);
  }
  __syncthreads();
#pragma unroll
  for (int r = 0; r < 4; r++) {
    int n = nt * 32 + ty + r * 8;
    int k = kt * 32 + tx;
    WT[(size_t)n * K + k] = tile[tx][ty + r * 8];
  }
}

__global__ void k_sampw(Params p) {
  int s = blockIdx.x;
  int row = p.nce[s];
  for (int j = threadIdx.x; j < HD; j += 256)
    p.sampWT[s * HD + j] = f2b(p.smw[(size_t)row * HD + j]);
  if (threadIdx.x == 0) p.sampb[s] = p.smb[row];
}

__global__ __launch_bounds__(256) void k_xproj(Params p) {
  int blk = blockIdx.x;
  int mt = blk >> 5, nt = blk & 31;
  int w = threadIdx.x >> 6, lane = threadIdx.x & 63, l15 = lane & 15, g = lane >> 4;
  int row0 = mt * 128 + w * 32, cb = nt * 32;
  const short* ap[2];
#pragma unroll
  for (int mi = 0; mi < 2; mi++) {
    int r = row0 + mi * 16 + l15;
    int tt = r >> 7, bb = r & 127;
    int tk = p.tok[bb * T_SEQ + tt];
    ap[mi] = p.embB + (size_t)tk * 256 + g * 8;
  }
  f32x4 z = {0.f, 0.f, 0.f, 0.f};
  Acc22 acc; acc.a[0][0] = z; acc.a[0][1] = z; acc.a[1][0] = z; acc.a[1][1] = z;
  const short* b0 = p.winT + (size_t)(cb + l15) * 256 + g * 8;
  const short* b1 = b0 + 16 * 256;
  for (int k = 0; k < 256; k += 32) {
    short8v av0 = *(const short8v*)(ap[0] + k);
    short8v av1 = *(const short8v*)(ap[1] + k);
    short8v bv0 = *(const short8v*)(b0 + k);
    short8v bv1 = *(const short8v*)(b1 + k);
    acc.a[0][0] = __builtin_amdgcn_mfma_f32_16x16x32_bf16(av0, bv0, acc.a[0][0], 0, 0, 0);
    acc.a[0][1] = __builtin_amdgcn_mfma_f32_16x16x32_bf16(av0, bv1, acc.a[0][1], 0, 0, 0);
    acc.a[1][0] = __builtin_amdgcn_mfma_f32_16x16x32_bf16(av1, bv0, acc.a[1][0], 0, 0, 0);
    acc.a[1][1] = __builtin_amdgcn_mfma_f32_16x16x32_bf16(av1, bv1, acc.a[1][1], 0, 0, 0);
  }
#pragma unroll
  for (int mi = 0; mi < 2; mi++)
#pragma unroll
    for (int ni = 0; ni < 2; ni++)
#pragma unroll
      for (int i = 0; i < 4; i++) {
        int row = row0 + mi * 16 + g * 4 + i;
        int col = cb + ni * 16 + l15;
        p.X[(size_t)row * HD + col] = f2b(acc.a[mi][ni][i] + p.binp[col]);
      }
}

__global__ __launch_bounds__(256) void k_gxc0init(Params p) {
  int blk = blockIdx.x;
  int w = threadIdx.x >> 6, lane = threadIdx.x & 63, l15 = lane & 15, g = lane >> 4;
  int row0 = w * 32, cb = blk * 32;
  Acc22 acc;
  gemm_wave(p.X, HD, p.WXC0T, HD, row0, cb, HD, acc);
#pragma unroll
  for (int mi = 0; mi < 2; mi++)
#pragma unroll
    for (int ni = 0; ni < 2; ni++)
#pragma unroll
      for (int i = 0; i < 4; i++) {
        int row = row0 + mi * 16 + g * 4 + i;
        int col = cb + ni * 16 + l15;
        p.gxc0a[row * 3072 + col] = acc.a[mi][ni][i];
      }
}

// ---------- persistent recurrence with LDS-pinned weights (unchanged body) ----------

extern __shared__ short wlds[];

static __device__ __forceinline__ f32x4 tile16_lds(const short* __restrict__ A,
    int slot, int arow, int l15, int g8) {
  f32x4 acc = {0.f, 0.f, 0.f, 0.f};
  const short* ap = A + (size_t)arow * HD + g8;
  const int xoff = (l15 & 7) << 3;
  const int bbase = slot * 16384 + l15 * 1024;
#pragma unroll 8
  for (int ks = 0; ks < 32; ++ks) {
    short8v av = *(const short8v*)(ap + ks * 32);
    short8v bv = *(const short8v*)&wlds[bbase + ((g8 + ks * 32) ^ xoff)];
    acc = __builtin_amdgcn_mfma_f32_16x16x32_bf16(av, bv, acc, 0, 0, 0);
  }
  return acc;
}

__global__ __launch_bounds__(512, 2) void k_recur(Params p, int* bar) {
  const int blk = blockIdx.x;
  const int tid = threadIdx.x;
  const int w = tid >> 6, lane = tid & 63, l15 = lane & 15, g = lane >> 4;
  const int arow = w * 16 + l15;
  const int g8 = g * 8;
  const int rbase = w * 16 + g * 4;

  // slice sources
  const short* src[3];
  int ct1, ct2;
  if (blk < 128) {
    ct1 = blk;
    src[0] = p.WXC1T + (size_t)blk * 16 * HD;
    src[1] = p.WhgT1 + (size_t)blk * 16 * HD;
    if (blk < 64) { ct2 = blk;       src[2] = p.WhcT0 + (size_t)ct2 * 16 * HD; }
    else          { ct2 = blk - 64;  src[2] = p.WhcT1 + (size_t)ct2 * 16 * HD; }
  } else if (blk < 192) {
    int b = blk - 128; ct1 = 2 * b; ct2 = b;
    src[0] = p.WhgT0 + (size_t)(2 * b) * 16 * HD;
    src[1] = p.WhgT0 + (size_t)(2 * b + 1) * 16 * HD;
    src[2] = p.WXC0T + (size_t)b * 16 * HD;
  } else {
    int b = blk - 192; ct1 = b; ct2 = 64 + 2 * b;
    src[0] = p.WXC1T + ((size_t)2048 + b * 16) * HD;
    src[1] = p.WXC0T + (size_t)(64 + 2 * b) * 16 * HD;
    src[2] = p.WXC0T + (size_t)(65 + 2 * b) * 16 * HD;
  }
  // preload 3 x 32KB with XOR swizzle
#pragma unroll
  for (int slot = 0; slot < 3; ++slot) {
    const short* s0 = src[slot];
    for (int j = tid; j < 2048; j += 512) {
      int col = j >> 7, k = (j & 127) * 8;
      short8v v = *(const short8v*)(s0 + col * HD + k);
      *(short8v*)&wlds[slot * 16384 + col * 1024 + (k ^ ((col & 7) << 3))] = v;
    }
  }
  __syncthreads();

  for (int s = 0; s <= T_SEQ; ++s) {
    const float* gxc_s = (s & 1) ? p.gxc0b : p.gxc0a;
    // -------- P1 --------
    if (blk < 128) {
      if (s >= 1) {
        f32x4 x1 = tile16_lds(p.h0b, 0, arow, l15, g8);       // gx1[s-1]
        f32x4 h1g = tile16_lds(p.h1b, 1, arow, l15, g8);      // gh1[s-1]
        int c = ct1 * 16 + l15;
#pragma unroll
        for (int i = 0; i < 4; ++i) {
          int r = rbase + i;
          float gv = sigm(p.ag[2048 + c] * x1[i] * h1g[i] + p.b1g[2048 + c] * x1[i] +
                          p.b2g[2048 + c] * h1g[i] + p.bg[2048 + c]);
          if (c < HD) p.rh1b[r * HD + c] = f2b(gv * p.h1f[r * HD + c]);
          else        p.u1[r * HD + c - HD] = gv;
        }
      }
    } else if (blk < 192) {
      if (s < T_SEQ) {
#pragma unroll
        for (int sl = 0; sl < 2; ++sl) {
          f32x4 gh = tile16_lds(p.h0b, sl, arow, l15, g8);    // gh0[s]
          int c = (ct1 + sl) * 16 + l15;
#pragma unroll
          for (int i = 0; i < 4; ++i) {
            int r = rbase + i;
            float gx = gxc_s[r * 3072 + c];
            float gv = sigm(p.ag[c] * gx * gh[i] + p.b1g[c] * gx +
                            p.b2g[c] * gh[i] + p.bg[c]);
            if (c < HD) p.rh0b[r * HD + c] = f2b(gv * p.h0f[r * HD + c]);
            else        p.u0[r * HD + c - HD] = gv;
          }
        }
      }
    } else {
      if (s >= 1) {
        f32x4 cx = tile16_lds(p.h0b, 0, arow, l15, g8);       // cx1[s-1]
        int c = ct1 * 16 + l15;
#pragma unroll
        for (int i = 0; i < 4; ++i) p.cx1[(rbase + i) * HD + c] = cx[i];
      }
    }
    gbar(bar);
    // -------- P2 --------
    float* gxc_n = ((s + 1) & 1) ? p.gxc0b : p.gxc0a;
    if (blk < 64) {
      if (s < T_SEQ) {
        f32x4 ch = tile16_lds(p.rh0b, 2, arow, l15, g8);      // ch0[s]
        int c = ct2 * 16 + l15;
#pragma unroll
        for (int i = 0; i < 4; ++i) {
          int r = rbase + i;
          float cx = gxc_s[r * 3072 + 2048 + c];
          float cv = tanhf(p.ac[c] * cx * ch[i] + p.b1c[c] * cx +
                           p.b2c[c] * ch[i] + p.bc[c]);
          float un = p.u0[r * HD + c];
          float hn = un * p.h0f[r * HD + c] + (1.f - un) * cv;
          p.h0f[r * HD + c] = hn;
          p.h0b[r * HD + c] = f2b(hn);
        }
      }
    } else if (blk < 128) {
      if (s >= 1) {
        f32x4 ch = tile16_lds(p.rh1b, 2, arow, l15, g8);      // ch1[s-1]
        int c = ct2 * 16 + l15;
#pragma unroll
        for (int i = 0; i < 4; ++i) {
          int r = rbase + i;
          float cx = p.cx1[r * HD + c];
          float cv = tanhf(p.ac[HD + c] * cx * ch[i] + p.b1c[HD + c] * cx +
                           p.b2c[HD + c] * ch[i] + p.bc[HD + c]);
          float un = p.u1[r * HD + c];
          float hn = un * p.h1f[r * HD + c] + (1.f - un) * cv;
          p.h1f[r * HD + c] = hn;
          p.h1b[r * HD + c] = f2b(hn);
          p.OUTb[((size_t)(s - 1) * BATCH + r) * HD + c] = f2b(hn);
        }
      }
    } else if (blk < 192) {
      if (s + 1 < T_SEQ) {
        const short* A = p.X + (size_t)(s + 1) * BATCH * HD;
        f32x4 v = tile16_lds(A, 2, arow, l15, g8);            // gxc0[s+1] cols 0..1023
        int c = ct2 * 16 + l15;
#pragma unroll
        for (int i = 0; i < 4; ++i) gxc_n[(rbase + i) * 3072 + c] = v[i];
      }
    } else {
      if (s + 1 < T_SEQ) {
        const short* A = p.X + (size_t)(s + 1) * BATCH * HD;
#pragma unroll
        for (int sl = 0; sl < 2; ++sl) {
          f32x4 v = tile16_lds(A, 1 + sl, arow, l15, g8);     // cols 1024..3071
          int c = (ct2 + sl) * 16 + l15;
#pragma unroll
          for (int i = 0; i < 4; ++i) gxc_n[(rbase + i) * 3072 + c] = v[i];
        }
      }
    }
    gbar(bar);
  }
}

// ---------- NCE (unchanged) ----------

__global__ __launch_bounds__(256) void k_nce_gemm(Params p) {
  int blk = blockIdx.x;
  int mt = blk >> 1, nt = blk & 1;
  int w = threadIdx.x >> 6, lane = threadIdx.x & 63, l15 = lane & 15, g = lane >> 4;
  int row0 = w * 32, cb = nt * 32;
  Acc22 acc;
  gemm_wave(p.OUTb + (size_t)mt * 128 * HD, HD, p.sampWT, HD, row0, cb, HD, acc);
#pragma unroll
  for (int mi = 0; mi < 2; mi++)
#pragma unroll
    for (int ni = 0; ni < 2; ni++)
#pragma unroll
      for (int i = 0; i < 4; i++) {
        int row = mt * 128 + row0 + mi * 16 + g * 4 + i;
        int col = cb + ni * 16 + l15;
        p.slog[(size_t)row * 64 + col] = acc.a[mi][ni][i] + p.sampb[col];
      }
}

__global__ __launch_bounds__(256) void k_loss(Params p) {
  __shared__ float acc4[4];
  int w = threadIdx.x >> 6, lane = threadIdx.x & 63;
  int r = blockIdx.x * 4 + w;
  int b = r >> 8, t = r & 255;
  int q = t * BATCH + b;
  int label = p.tgt[r];
  const short* orow = p.OUTb + (size_t)q * HD;
  const float4* t4 = (const float4*)(p.smw + (size_t)label * HD) + lane * 4;
  float s = 0.f;
  const short8v* o8 = (const short8v*)(orow + lane * 16);
#pragma unroll
  for (int u2 = 0; u2 < 2; u2++) {
    short8v ov = o8[u2];
    float4 ta = t4[u2 * 2], tb = t4[u2 * 2 + 1];
    s += b2f(ov[0]) * ta.x + b2f(ov[1]) * ta.y + b2f(ov[2]) * ta.z + b2f(ov[3]) * ta.w;
    s += b2f(ov[4]) * tb.x + b2f(ov[5]) * tb.y + b2f(ov[6]) * tb.z + b2f(ov[7]) * tb.w;
  }
  for (int off = 32; off; off >>= 1) s += __shfl_down(s, off);
  float tl = __shfl(s, 0) + p.smb[label];
  float sl = p.slog[(size_t)q * 64 + lane];
  float v = splus(sl);
  for (int off = 32; off; off >>= 1) v += __shfl_down(v, off);
  if (lane == 0) acc4[w] = v + splus(-tl);
  __syncthreads();
  if (threadIdx.x == 0)
    atomicAdd(p.dout, (acc4[0] + acc4[1] + acc4[2] + acc4[3]) * (1.f / 32768.f));
}

// ---------- host ----------

extern "C" void kernel_launch(void* const* d_in, const int* in_sizes, int n_in,
                              void* d_out, int out_size, void* d_ws, size_t ws_size,
                              hipStream_t stream) {
  Params p;
  p.tok = (const int*)d_in[0];
  p.tgt = (const int*)d_in[1];
  p.nce = (const int*)d_in[2];
  p.emb = (const float*)d_in[3];
  p.win = (const float*)d_in[4];
  p.binp = (const float*)d_in[5];
  const float* Wxg = (const float*)d_in[6];
  const float* Whg = (const float*)d_in[7];
  p.ag = (const float*)d_in[8];
  p.b1g = (const float*)d_in[9];
  p.b2g = (const float*)d_in[10];
  p.bg = (const float*)d_in[11];
  const float* Wxc = (const float*)d_in[12];
  const float* Whc = (const float*)d_in[13];
  p.ac = (const float*)d_in[14];
  p.b1c = (const float*)d_in[15];
  p.b2c = (const float*)d_in[16];
  p.bc = (const float*)d_in[17];
  p.smw = (const float*)d_in[18];
  p.smb = (const float*)d_in[19];
  p.dout = (float*)d_out;

  char* w = (char*)d_ws;
  size_t off = 0;
  auto alloc = [&](size_t bytes) -> void* {
    void* q = w + off;
    off += (bytes + 255) & ~(size_t)255;
    return q;
  };
  p.embB   = (short*)alloc((size_t)16384 * 256 * 2);
  p.winT   = (short*)alloc((size_t)1024 * 256 * 2);
  p.WhgT0  = (short*)alloc((size_t)2048 * 1024 * 2);
  p.WhgT1  = (short*)alloc((size_t)2048 * 1024 * 2);
  p.WhcT0  = (short*)alloc((size_t)1024 * 1024 * 2);
  p.WhcT1  = (short*)alloc((size_t)1024 * 1024 * 2);
  p.WXC0T  = (short*)alloc((size_t)3072 * 1024 * 2);
  p.WXC1T  = (short*)alloc((size_t)3072 * 1024 * 2);
  p.sampWT = (short*)alloc((size_t)64 * 1024 * 2);
  p.sampb  = (float*)alloc(64 * 4);
  p.X      = (short*)alloc((size_t)32768 * 1024 * 2);
  p.OUTb   = (short*)alloc((size_t)32768 * 1024 * 2);
  p.h0f    = (float*)alloc((size_t)BATCH * HD * 4);   // h0f..h1b contiguous (zeroed together)
  p.h1f    = (float*)alloc((size_t)BATCH * HD * 4);
  p.h0b    = (short*)alloc((size_t)BATCH * HD * 2);
  p.h1b    = (short*)alloc((size_t)BATCH * HD * 2);
  p.rh0b   = (short*)alloc((size_t)BATCH * HD * 2);
  p.rh1b   = (short*)alloc((size_t)BATCH * HD * 2);
  p.u0     = (float*)alloc((size_t)BATCH * HD * 4);
  p.u1     = (float*)alloc((size_t)BATCH * HD * 4);
  p.cx1    = (float*)alloc((size_t)BATCH * HD * 4);
  p.gxc0a  = (float*)alloc((size_t)BATCH * 3072 * 4);
  p.gxc0b  = (float*)alloc((size_t)BATCH * 3072 * 4);
  p.slog   = (float*)alloc((size_t)32768 * 64 * 4);
  int* bar = (int*)alloc(8192);

  // allow >64KB dynamic LDS for k_recur (idempotent; host-side, capture-safe)
  static bool attr_set = false;
  if (!attr_set) {
    hipFuncSetAttribute((const void*)k_recur,
                        hipFuncAttributeMaxDynamicSharedMemorySize, 98304);
    attr_set = true;
  }

  // zero h state + barrier + d_out
  k_zero<<<1536, 256, 0, stream>>>(p.h0f, 393216, p.dout, bar);
  // fp32 -> bf16 conversion (embedding only)
  k_conv<<<4096, 256, 0, stream>>>(p.emb, p.embB, 16384 * 256);
  // weight transposes (W [K][N] fp32 -> WT [N][K] bf16)
  dim3 tb(32, 8);
  k_transpose<<<dim3(32, 8),  tb, 0, stream>>>(p.win, p.winT, 256, 1024);
  k_transpose<<<dim3(64, 32), tb, 0, stream>>>(Whg, p.WhgT0, 1024, 2048);
  k_transpose<<<dim3(64, 32), tb, 0, stream>>>(Whg + (size_t)1024 * 2048, p.WhgT1, 1024, 2048);
  k_transpose<<<dim3(32, 32), tb, 0, stream>>>(Whc, p.WhcT0, 1024, 1024);
  k_transpose<<<dim3(32, 32), tb, 0, stream>>>(Whc + (size_t)1024 * 1024, p.WhcT1, 1024, 1024);
  k_transpose<<<dim3(64, 32), tb, 0, stream>>>(Wxg, p.WXC0T, 1024, 2048);
  k_transpose<<<dim3(32, 32), tb, 0, stream>>>(Wxc, p.WXC0T + (size_t)2048 * 1024, 1024, 1024);
  k_transpose<<<dim3(64, 32), tb, 0, stream>>>(Wxg + (size_t)1024 * 2048, p.WXC1T, 1024, 2048);
  k_transpose<<<dim3(32, 32), tb, 0, stream>>>(Wxc + (size_t)1024 * 1024, p.WXC1T + (size_t)2048 * 1024, 1024, 1024);
  // NCE sample weights
  k_sampw<<<64, 256, 0, stream>>>(p);
  // X = emb_gather @ win + bin  (layout [t][b][:])
  k_xproj<<<8192, 256, 0, stream>>>(p);
  // gxc0 for t=0
  k_gxc0init<<<96, 256, 0, stream>>>(p);

  // persistent recurrence with LDS-pinned weights (96KB dynamic LDS)
  k_recur<<<NBLK, 512, 98304, stream>>>(p, bar);

  // NCE tail
  k_nce_gemm<<<512, 256, 0, stream>>>(p);
  k_loss<<<8192, 256, 0, stream>>>(p);
}